// Round 2
// baseline (1154.411 us; speedup 1.0000x reference)
//
#include <hip/hip_runtime.h>
#include <hip/hip_bf16.h>

#define N_NODES 50000
#define N_EDGES 800000
#define FDIM 256
#define N_LAYERS 3

// ---------------- preprocessing (once per call; layer-invariant) ----------------

__global__ void deg_count_kernel(const int* __restrict__ dst,
                                 const float* __restrict__ w,
                                 float* __restrict__ deg,
                                 int* __restrict__ cnt, int E) {
  int e = blockIdx.x * blockDim.x + threadIdx.x;
  if (e < E) {
    int d = dst[e];
    atomicAdd(&deg[d], w[e]);
    atomicAdd(&cnt[d], 1);
  }
}

__global__ void dinv_kernel(const float* __restrict__ deg,
                            float* __restrict__ dinv, int n) {
  int i = blockIdx.x * blockDim.x + threadIdx.x;
  if (i < n) {
    float d = deg[i];
    dinv[i] = (d > 0.f) ? (1.f / sqrtf(d)) : 0.f;
  }
}

// single-block scan over N_NODES counts -> exclusive offsets (CSR row ptr)
__global__ __launch_bounds__(1024)
void scan_kernel(const int* __restrict__ cnt, int* __restrict__ offs,
                 int* __restrict__ cursor, int n) {
  __shared__ int wsums[16];
  __shared__ int carry_s;
  int t = threadIdx.x;
  int lane = t & 63, wid = t >> 6;
  if (t == 0) carry_s = 0;
  __syncthreads();
  for (int base = 0; base < n; base += 1024) {
    int i = base + t;
    int v = (i < n) ? cnt[i] : 0;
    int incl = v;
    #pragma unroll
    for (int d = 1; d < 64; d <<= 1) {
      int tmp = __shfl_up(incl, d, 64);
      if (lane >= d) incl += tmp;
    }
    if (lane == 63) wsums[wid] = incl;
    __syncthreads();
    if (t == 0) {
      int s = carry_s;
      #pragma unroll
      for (int k = 0; k < 16; ++k) { int tt = wsums[k]; wsums[k] = s; s += tt; }
      carry_s = s;
    }
    __syncthreads();
    int excl = incl - v + wsums[wid];
    if (i < n) { offs[i] = excl; cursor[i] = excl; }
    __syncthreads();
  }
  if (t == 0) offs[n] = carry_s;
}

// bucket edges by dst; pre-permute src index and edge norm into CSR order
__global__ void scatter_kernel(const int* __restrict__ src,
                               const int* __restrict__ dst,
                               const float* __restrict__ w,
                               const float* __restrict__ dinv,
                               int* __restrict__ cursor,
                               int* __restrict__ src_s,
                               float* __restrict__ norm_s, int E) {
  int e = blockIdx.x * blockDim.x + threadIdx.x;
  if (e < E) {
    int s = src[e], d = dst[e];
    int pos = atomicAdd(&cursor[d], 1);
    src_s[pos] = s;
    norm_s[pos] = dinv[s] * w[e] * dinv[d];
  }
}

// ---------------- fused dual GEMM: h = x@Wi ; r = x@Wr + b ----------------
// fp32 vector-ALU GEMM (no fp32 MFMA on CDNA4). 64x128 tile, 4x8 micro-tile.

#define BM 64
#define BN 128
#define BK 16

__global__ __launch_bounds__(256)
void gemm_kernel(const float* __restrict__ x,
                 const float* __restrict__ Wi,
                 const float* __restrict__ Wr,
                 const float* __restrict__ bias,
                 float* __restrict__ h,
                 float* __restrict__ r, int M) {
  __shared__ float xs[BK][BM];    // transposed x tile: xs[k][m]
  __shared__ float wsh[BK][BN];
  int t = threadIdx.x;
  int rowBase = blockIdx.x * BM;
  int colSel = blockIdx.y;                 // 0..3 over logical 512-wide N
  bool isRoot = (colSel >= 2);
  const float* __restrict__ W = isRoot ? Wr : Wi;
  int jBase = (colSel & 1) * BN;

  float acc[4][8];
  #pragma unroll
  for (int i = 0; i < 4; ++i)
    #pragma unroll
    for (int j = 0; j < 8; ++j) acc[i][j] = 0.f;

  int lm = t >> 2;            // 0..63  (row in x tile)
  int lk = (t & 3) * 4;       // 0,4,8,12 (k group)
  int wk = t >> 4;            // 0..15  (k row in W tile)
  int wj = (t & 15) * 8;      // 0..120 (col group)

  int tm = (t >> 4) * 4;      // 0..60
  int tn = (t & 15) * 8;      // 0..120

  for (int k0 = 0; k0 < FDIM; k0 += BK) {
    float4 xv = make_float4(0.f, 0.f, 0.f, 0.f);
    int grow = rowBase + lm;
    if (grow < M)
      xv = *reinterpret_cast<const float4*>(x + (size_t)grow * FDIM + k0 + lk);
    xs[lk + 0][lm] = xv.x;
    xs[lk + 1][lm] = xv.y;
    xs[lk + 2][lm] = xv.z;
    xs[lk + 3][lm] = xv.w;
    const float* wp = W + (size_t)(k0 + wk) * FDIM + jBase + wj;
    float4 wv0 = *reinterpret_cast<const float4*>(wp);
    float4 wv1 = *reinterpret_cast<const float4*>(wp + 4);
    *reinterpret_cast<float4*>(&wsh[wk][wj]) = wv0;
    *reinterpret_cast<float4*>(&wsh[wk][wj + 4]) = wv1;
    __syncthreads();

    #pragma unroll
    for (int k = 0; k < BK; ++k) {
      float a[4], b[8];
      #pragma unroll
      for (int i = 0; i < 4; ++i) a[i] = xs[k][tm + i];
      #pragma unroll
      for (int j = 0; j < 8; ++j) b[j] = wsh[k][tn + j];
      #pragma unroll
      for (int i = 0; i < 4; ++i)
        #pragma unroll
        for (int j = 0; j < 8; ++j)
          acc[i][j] += a[i] * b[j];
    }
    __syncthreads();
  }

  float bv[8];
  #pragma unroll
  for (int j = 0; j < 8; ++j)
    bv[j] = isRoot ? bias[jBase + tn + j] : 0.f;

  float* __restrict__ outp = isRoot ? r : h;
  #pragma unroll
  for (int i = 0; i < 4; ++i) {
    int row = rowBase + tm + i;
    if (row < M) {
      float4 o0, o1;
      o0.x = acc[i][0] + bv[0]; o0.y = acc[i][1] + bv[1];
      o0.z = acc[i][2] + bv[2]; o0.w = acc[i][3] + bv[3];
      o1.x = acc[i][4] + bv[4]; o1.y = acc[i][5] + bv[5];
      o1.z = acc[i][6] + bv[6]; o1.w = acc[i][7] + bv[7];
      float* op = outp + (size_t)row * FDIM + jBase + tn;
      *reinterpret_cast<float4*>(op) = o0;
      *reinterpret_cast<float4*>(op + 4) = o1;
    }
  }
}

// ---------------- aggregation: xout = relu(sum_e norm*h[src] + r) ----------------
// one wave per dst node; lane l owns features [4l, 4l+4) as float4

__global__ __launch_bounds__(256)
void agg_kernel(const float* __restrict__ h,
                const float* __restrict__ r,
                const float* __restrict__ norm_s,
                const int* __restrict__ src_s,
                const int* __restrict__ offs,
                float* __restrict__ xout, int n) {
  int node = blockIdx.x * 4 + (threadIdx.x >> 6);
  if (node >= n) return;
  int lane = threadIdx.x & 63;
  int beg = offs[node];
  int end = offs[node + 1];
  float4 acc = make_float4(0.f, 0.f, 0.f, 0.f);
  for (int j = beg; j < end; ++j) {
    int s = src_s[j];
    float wv = norm_s[j];
    float4 hv = *reinterpret_cast<const float4*>(h + (size_t)s * FDIM + lane * 4);
    acc.x += wv * hv.x; acc.y += wv * hv.y;
    acc.z += wv * hv.z; acc.w += wv * hv.w;
  }
  float4 rv = *reinterpret_cast<const float4*>(r + (size_t)node * FDIM + lane * 4);
  float4 o;
  o.x = fmaxf(acc.x + rv.x, 0.f);
  o.y = fmaxf(acc.y + rv.y, 0.f);
  o.z = fmaxf(acc.z + rv.z, 0.f);
  o.w = fmaxf(acc.w + rv.w, 0.f);
  *reinterpret_cast<float4*>(xout + (size_t)node * FDIM + lane * 4) = o;
}

// ---------------- launch ----------------

extern "C" void kernel_launch(void* const* d_in, const int* in_sizes, int n_in,
                              void* d_out, int out_size, void* d_ws, size_t ws_size,
                              hipStream_t stream) {
  (void)in_sizes; (void)n_in; (void)out_size; (void)ws_size;
  const float* x0   = (const float*)d_in[0];
  const int*   ei   = (const int*)d_in[1];
  const float* ea   = (const float*)d_in[2];
  const float* Wi_a = (const float*)d_in[3];
  const float* Wr_a = (const float*)d_in[4];
  const float* b_a  = (const float*)d_in[5];
  float* out = (float*)d_out;

  const int* src = ei;
  const int* dst = ei + N_EDGES;

  char* ws = (char*)d_ws;
  size_t off = 0;
  auto alloc = [&](size_t bytes) {
    char* p = ws + off;
    off += (bytes + 255) & ~(size_t)255;
    return p;
  };
  float* xbuf   = (float*)alloc((size_t)N_NODES * FDIM * 4);
  float* hbuf   = (float*)alloc((size_t)N_NODES * FDIM * 4);
  float* rbuf   = (float*)alloc((size_t)N_NODES * FDIM * 4);
  float* deg    = (float*)alloc((size_t)N_NODES * 4);
  float* dinv   = (float*)alloc((size_t)N_NODES * 4);
  int*   cnt    = (int*)alloc((size_t)N_NODES * 4);
  int*   offs   = (int*)alloc((size_t)(N_NODES + 1) * 4);
  int*   cursor = (int*)alloc((size_t)N_NODES * 4);
  int*   src_s  = (int*)alloc((size_t)N_EDGES * 4);
  float* norm_s = (float*)alloc((size_t)N_EDGES * 4);

  hipMemsetAsync(deg, 0, (size_t)N_NODES * 4, stream);
  hipMemsetAsync(cnt, 0, (size_t)N_NODES * 4, stream);

  deg_count_kernel<<<(N_EDGES + 255) / 256, 256, 0, stream>>>(dst, ea, deg, cnt, N_EDGES);
  dinv_kernel<<<(N_NODES + 255) / 256, 256, 0, stream>>>(deg, dinv, N_NODES);
  scan_kernel<<<1, 1024, 0, stream>>>(cnt, offs, cursor, N_NODES);
  scatter_kernel<<<(N_EDGES + 255) / 256, 256, 0, stream>>>(src, dst, ea, dinv, cursor,
                                                            src_s, norm_s, N_EDGES);

  dim3 ggrid((N_NODES + BM - 1) / BM, 4);
  for (int l = 0; l < N_LAYERS; ++l) {
    const float* xin = (l == 0) ? x0 : xbuf;
    float* xout = (l == N_LAYERS - 1) ? out : xbuf;
    gemm_kernel<<<ggrid, 256, 0, stream>>>(xin,
                                           Wi_a + (size_t)l * FDIM * FDIM,
                                           Wr_a + (size_t)l * FDIM * FDIM,
                                           b_a + (size_t)l * FDIM,
                                           hbuf, rbuf, N_NODES);
    agg_kernel<<<(N_NODES + 3) / 4, 256, 0, stream>>>(hbuf, rbuf, norm_s, src_s, offs,
                                                      xout, N_NODES);
  }
}

// Round 3
// 878.163 us; speedup vs baseline: 1.3146x; 1.3146x over previous
//
#include <hip/hip_runtime.h>
#include <hip/hip_bf16.h>

#define N_NODES 50000
#define N_EDGES 800000
#define FDIM 256
#define N_LAYERS 3

typedef __attribute__((ext_vector_type(8))) short bf16x8;
typedef __attribute__((ext_vector_type(4))) float f32x4;

// RNE fp32 -> bf16 bit conversion (inputs finite)
__device__ inline unsigned short f2bf(float f) {
  unsigned int u = __float_as_uint(f);
  unsigned int r = u + 0x7FFFu + ((u >> 16) & 1u);
  return (unsigned short)(r >> 16);
}
__device__ inline float bf2f(unsigned short s) {
  return __uint_as_float(((unsigned int)s) << 16);
}
__device__ inline void split2(float f, unsigned short& h, unsigned short& l) {
  h = f2bf(f);
  l = f2bf(f - bf2f(h));
}

#define GLOAD16(g, l) __builtin_amdgcn_global_load_lds( \
    (const __attribute__((address_space(1))) void*)(g), \
    (__attribute__((address_space(3))) void*)(l), 16, 0, 0)

// ---------------- preprocessing (once per call; layer-invariant) ----------------

__global__ void deg_count_kernel(const int* __restrict__ dst,
                                 const float* __restrict__ w,
                                 float* __restrict__ deg,
                                 int* __restrict__ cnt, int E) {
  int e = blockIdx.x * blockDim.x + threadIdx.x;
  if (e < E) {
    int d = dst[e];
    atomicAdd(&deg[d], w[e]);
    atomicAdd(&cnt[d], 1);
  }
}

__global__ void dinv_kernel(const float* __restrict__ deg,
                            float* __restrict__ dinv, int n) {
  int i = blockIdx.x * blockDim.x + threadIdx.x;
  if (i < n) {
    float d = deg[i];
    dinv[i] = (d > 0.f) ? (1.f / sqrtf(d)) : 0.f;
  }
}

__global__ __launch_bounds__(1024)
void scan_kernel(const int* __restrict__ cnt, int* __restrict__ offs,
                 int* __restrict__ cursor, int n) {
  __shared__ int wsums[16];
  __shared__ int carry_s;
  int t = threadIdx.x;
  int lane = t & 63, wid = t >> 6;
  if (t == 0) carry_s = 0;
  __syncthreads();
  for (int base = 0; base < n; base += 1024) {
    int i = base + t;
    int v = (i < n) ? cnt[i] : 0;
    int incl = v;
    #pragma unroll
    for (int d = 1; d < 64; d <<= 1) {
      int tmp = __shfl_up(incl, d, 64);
      if (lane >= d) incl += tmp;
    }
    if (lane == 63) wsums[wid] = incl;
    __syncthreads();
    if (t == 0) {
      int s = carry_s;
      #pragma unroll
      for (int k = 0; k < 16; ++k) { int tt = wsums[k]; wsums[k] = s; s += tt; }
      carry_s = s;
    }
    __syncthreads();
    int excl = incl - v + wsums[wid];
    if (i < n) { offs[i] = excl; cursor[i] = excl; }
    __syncthreads();
  }
  if (t == 0) offs[n] = carry_s;
}

__global__ void scatter_kernel(const int* __restrict__ src,
                               const int* __restrict__ dst,
                               const float* __restrict__ w,
                               const float* __restrict__ dinv,
                               int* __restrict__ cursor,
                               int* __restrict__ src_s,
                               float* __restrict__ norm_s, int E) {
  int e = blockIdx.x * blockDim.x + threadIdx.x;
  if (e < E) {
    int s = src[e], d = dst[e];
    int pos = atomicAdd(&cursor[d], 1);
    src_s[pos] = s;
    norm_s[pos] = dinv[s] * w[e] * dinv[d];
  }
}

// split x0 -> hi/lo bf16
__global__ void split_kernel(const float* __restrict__ x,
                             unsigned short* __restrict__ xhi,
                             unsigned short* __restrict__ xlo, int n4) {
  int i = blockIdx.x * blockDim.x + threadIdx.x;
  if (i < n4) {
    float4 v = reinterpret_cast<const float4*>(x)[i];
    ushort4 h, l;
    split2(v.x, h.x, l.x);
    split2(v.y, h.y, l.y);
    split2(v.z, h.z, l.z);
    split2(v.w, h.w, l.w);
    reinterpret_cast<ushort4*>(xhi)[i] = h;
    reinterpret_cast<ushort4*>(xlo)[i] = l;
  }
}

// transpose + split weights: Wt[mat][n][k] = W[mat][k][n], mat = layer*2 + {Wi,Wr}
__global__ __launch_bounds__(256)
void wsplit_kernel(const float* __restrict__ Wi_a,
                   const float* __restrict__ Wr_a,
                   unsigned short* __restrict__ wthi,
                   unsigned short* __restrict__ wtlo) {
  __shared__ float tile[32][33];
  int m6 = blockIdx.x >> 6;            // 0..5
  int tid = blockIdx.x & 63;
  int tk = (tid >> 3) * 32;
  int tn = (tid & 7) * 32;
  int layer = m6 >> 1;
  const float* W = ((m6 & 1) ? Wr_a : Wi_a) + (size_t)layer * FDIM * FDIM;
  int t = threadIdx.x;
  int lr = t >> 3;            // 0..31
  int lc = (t & 7) * 4;       // 0..28
  float4 v = *reinterpret_cast<const float4*>(W + (size_t)(tk + lr) * FDIM + tn + lc);
  tile[lr][lc + 0] = v.x; tile[lr][lc + 1] = v.y;
  tile[lr][lc + 2] = v.z; tile[lr][lc + 3] = v.w;
  __syncthreads();
  // write transposed: row n'' = tn+lr, cols k'' = tk+lc..+3
  ushort4 h, l;
  split2(tile[lc + 0][lr], h.x, l.x);
  split2(tile[lc + 1][lr], h.y, l.y);
  split2(tile[lc + 2][lr], h.z, l.z);
  split2(tile[lc + 3][lr], h.w, l.w);
  size_t o = ((size_t)m6 * FDIM + tn + lr) * FDIM + tk + lc;
  *reinterpret_cast<ushort4*>(wthi + o) = h;
  *reinterpret_cast<ushort4*>(wtlo + o) = l;
}

// ---------------- split-bf16 MFMA dual GEMM: h = x@Wi ; r = x@Wr + b ----------
// 128x128 tile, BK=32, 4 waves (2x2), each wave 4x4 16x16x32 frags, 4-term split.
// LDS tiles [128 outdim][32 k] bf16, XOR swizzle slot^=(row>>1)&3 (both sides).

__global__ __launch_bounds__(256, 2)
void gemm_split_kernel(const unsigned short* __restrict__ xhi,
                       const unsigned short* __restrict__ xlo,
                       const unsigned short* __restrict__ wthi,  // [2][256][256]
                       const unsigned short* __restrict__ wtlo,
                       const float* __restrict__ bias,
                       float* __restrict__ h,
                       float* __restrict__ r, int M) {
  __shared__ __align__(16) unsigned char smem[32768];
  const int t = threadIdx.x;
  const int lane = t & 63;
  const int w = t >> 6;
  const int rowBase = blockIdx.x * 128;
  const int colSel = blockIdx.y;
  const int isRoot = colSel >> 1;
  const int nBase = (colSel & 1) * 128;
  const unsigned short* whi = wthi + (size_t)isRoot * FDIM * FDIM;
  const unsigned short* wlo = wtlo + (size_t)isRoot * FDIM * FDIM;

  const int wm = (w >> 1) * 64;
  const int wn = (w & 1) * 64;

  f32x4 acc[4][4];
  #pragma unroll
  for (int i = 0; i < 4; ++i)
    #pragma unroll
    for (int j = 0; j < 4; ++j)
      acc[i][j] = (f32x4)(0.f);

  for (int k0 = 0; k0 < FDIM; k0 += 32) {
    #pragma unroll
    for (int j = 0; j < 2; ++j) {
      int s = j * 256 + t;
      int rr = s >> 2;
      int sl = (s & 3) ^ ((rr >> 1) & 3);   // inverse-swizzled k-slot (involution)
      int xrow = rowBase + rr; if (xrow >= M) xrow = M - 1;
      const unsigned short* ga = xhi + (size_t)xrow * FDIM + k0 + sl * 8;
      const unsigned short* gb = xlo + (size_t)xrow * FDIM + k0 + sl * 8;
      const unsigned short* gc = whi + (size_t)(nBase + rr) * FDIM + k0 + sl * 8;
      const unsigned short* gd = wlo + (size_t)(nBase + rr) * FDIM + k0 + sl * 8;
      GLOAD16(ga, smem + s * 16);
      GLOAD16(gb, smem + 8192 + s * 16);
      GLOAD16(gc, smem + 16384 + s * 16);
      GLOAD16(gd, smem + 24576 + s * 16);
    }
    __syncthreads();

    bf16x8 ah[4], al[4], bh[4], bl[4];
    const int q = lane >> 4;
    #pragma unroll
    for (int i = 0; i < 4; ++i) {
      int Ra = wm + i * 16 + (lane & 15);
      int offa = Ra * 64 + ((q ^ ((Ra >> 1) & 3)) * 16);
      ah[i] = *reinterpret_cast<const bf16x8*>(smem + offa);
      al[i] = *reinterpret_cast<const bf16x8*>(smem + 8192 + offa);
      int Rb = wn + i * 16 + (lane & 15);
      int offb = Rb * 64 + ((q ^ ((Rb >> 1) & 3)) * 16);
      bh[i] = *reinterpret_cast<const bf16x8*>(smem + 16384 + offb);
      bl[i] = *reinterpret_cast<const bf16x8*>(smem + 24576 + offb);
    }
    #pragma unroll
    for (int i = 0; i < 4; ++i)
      #pragma unroll
      for (int j = 0; j < 4; ++j) {
        acc[i][j] = __builtin_amdgcn_mfma_f32_16x16x32_bf16(al[i], bl[j], acc[i][j], 0, 0, 0);
        acc[i][j] = __builtin_amdgcn_mfma_f32_16x16x32_bf16(ah[i], bl[j], acc[i][j], 0, 0, 0);
        acc[i][j] = __builtin_amdgcn_mfma_f32_16x16x32_bf16(al[i], bh[j], acc[i][j], 0, 0, 0);
        acc[i][j] = __builtin_amdgcn_mfma_f32_16x16x32_bf16(ah[i], bh[j], acc[i][j], 0, 0, 0);
      }
    __syncthreads();
  }

  float* __restrict__ outp = isRoot ? r : h;
  const int cr = lane & 15;
  const int r4 = (lane >> 4) * 4;
  #pragma unroll
  for (int i = 0; i < 4; ++i)
    #pragma unroll
    for (int j = 0; j < 4; ++j) {
      int col = nBase + wn + j * 16 + cr;
      float badd = isRoot ? bias[col] : 0.f;
      #pragma unroll
      for (int e = 0; e < 4; ++e) {
        int row = rowBase + wm + i * 16 + r4 + e;
        if (row < M) outp[(size_t)row * FDIM + col] = acc[i][j][e] + badd;
      }
    }
}

// ---------------- aggregation: xout = relu(sum_e norm*h[src] + r) --------------
// one wave per dst node; epilogue writes hi/lo bf16 for next layer, or fp32 out.

__global__ __launch_bounds__(256)
void agg_kernel(const float* __restrict__ h,
                const float* __restrict__ r,
                const float* __restrict__ norm_s,
                const int* __restrict__ src_s,
                const int* __restrict__ offs,
                float* __restrict__ out,
                unsigned short* __restrict__ oh,
                unsigned short* __restrict__ ol,
                int writeFinal, int n) {
  int node = blockIdx.x * 4 + (threadIdx.x >> 6);
  if (node >= n) return;
  int lane = threadIdx.x & 63;
  int beg = offs[node];
  int end = offs[node + 1];
  float4 acc = make_float4(0.f, 0.f, 0.f, 0.f);
  for (int j = beg; j < end; ++j) {
    int s = src_s[j];
    float wv = norm_s[j];
    float4 hv = *reinterpret_cast<const float4*>(h + (size_t)s * FDIM + lane * 4);
    acc.x += wv * hv.x; acc.y += wv * hv.y;
    acc.z += wv * hv.z; acc.w += wv * hv.w;
  }
  float4 rv = *reinterpret_cast<const float4*>(r + (size_t)node * FDIM + lane * 4);
  float4 o;
  o.x = fmaxf(acc.x + rv.x, 0.f);
  o.y = fmaxf(acc.y + rv.y, 0.f);
  o.z = fmaxf(acc.z + rv.z, 0.f);
  o.w = fmaxf(acc.w + rv.w, 0.f);
  size_t base = (size_t)node * FDIM + lane * 4;
  if (writeFinal) {
    *reinterpret_cast<float4*>(out + base) = o;
  } else {
    ushort4 hh, ll;
    split2(o.x, hh.x, ll.x);
    split2(o.y, hh.y, ll.y);
    split2(o.z, hh.z, ll.z);
    split2(o.w, hh.w, ll.w);
    *reinterpret_cast<ushort4*>(oh + base) = hh;
    *reinterpret_cast<ushort4*>(ol + base) = ll;
  }
}

// ---------------- launch ----------------

extern "C" void kernel_launch(void* const* d_in, const int* in_sizes, int n_in,
                              void* d_out, int out_size, void* d_ws, size_t ws_size,
                              hipStream_t stream) {
  (void)in_sizes; (void)n_in; (void)out_size; (void)ws_size;
  const float* x0   = (const float*)d_in[0];
  const int*   ei   = (const int*)d_in[1];
  const float* ea   = (const float*)d_in[2];
  const float* Wi_a = (const float*)d_in[3];
  const float* Wr_a = (const float*)d_in[4];
  const float* b_a  = (const float*)d_in[5];
  float* out = (float*)d_out;

  const int* src = ei;
  const int* dst = ei + N_EDGES;

  char* ws = (char*)d_ws;
  size_t off = 0;
  auto alloc = [&](size_t bytes) {
    char* p = ws + off;
    off += (bytes + 255) & ~(size_t)255;
    return p;
  };
  float* hbuf   = (float*)alloc((size_t)N_NODES * FDIM * 4);
  float* rbuf   = (float*)alloc((size_t)N_NODES * FDIM * 4);
  unsigned short* xhi = (unsigned short*)alloc((size_t)N_NODES * FDIM * 2);
  unsigned short* xlo = (unsigned short*)alloc((size_t)N_NODES * FDIM * 2);
  unsigned short* wthi = (unsigned short*)alloc((size_t)N_LAYERS * 2 * FDIM * FDIM * 2);
  unsigned short* wtlo = (unsigned short*)alloc((size_t)N_LAYERS * 2 * FDIM * FDIM * 2);
  float* deg    = (float*)alloc((size_t)N_NODES * 4);
  float* dinv   = (float*)alloc((size_t)N_NODES * 4);
  int*   cnt    = (int*)alloc((size_t)N_NODES * 4);
  int*   offs   = (int*)alloc((size_t)(N_NODES + 1) * 4);
  int*   cursor = (int*)alloc((size_t)N_NODES * 4);
  int*   src_s  = (int*)alloc((size_t)N_EDGES * 4);
  float* norm_s = (float*)alloc((size_t)N_EDGES * 4);

  hipMemsetAsync(deg, 0, (size_t)N_NODES * 4, stream);
  hipMemsetAsync(cnt, 0, (size_t)N_NODES * 4, stream);

  deg_count_kernel<<<(N_EDGES + 255) / 256, 256, 0, stream>>>(dst, ea, deg, cnt, N_EDGES);
  dinv_kernel<<<(N_NODES + 255) / 256, 256, 0, stream>>>(deg, dinv, N_NODES);
  scan_kernel<<<1, 1024, 0, stream>>>(cnt, offs, cursor, N_NODES);
  scatter_kernel<<<(N_EDGES + 255) / 256, 256, 0, stream>>>(src, dst, ea, dinv, cursor,
                                                            src_s, norm_s, N_EDGES);
  wsplit_kernel<<<6 * 64, 256, 0, stream>>>(Wi_a, Wr_a, wthi, wtlo);
  int n4 = N_NODES * FDIM / 4;
  split_kernel<<<(n4 + 255) / 256, 256, 0, stream>>>(x0, xhi, xlo, n4);

  dim3 ggrid((N_NODES + 127) / 128, 4);
  for (int l = 0; l < N_LAYERS; ++l) {
    gemm_split_kernel<<<ggrid, 256, 0, stream>>>(
        xhi, xlo,
        wthi + (size_t)l * 2 * FDIM * FDIM,
        wtlo + (size_t)l * 2 * FDIM * FDIM,
        b_a + (size_t)l * FDIM,
        hbuf, rbuf, N_NODES);
    int writeFinal = (l == N_LAYERS - 1) ? 1 : 0;
    agg_kernel<<<(N_NODES + 3) / 4, 256, 0, stream>>>(hbuf, rbuf, norm_s, src_s, offs,
                                                      out, xhi, xlo, writeFinal, N_NODES);
  }
}

// Round 5
// 733.275 us; speedup vs baseline: 1.5743x; 1.1976x over previous
//
#include <hip/hip_runtime.h>
#include <hip/hip_bf16.h>

#define N_NODES 50000
#define N_EDGES 800000
#define FDIM 256
#define N_LAYERS 3

typedef __attribute__((ext_vector_type(8))) short bf16x8;
typedef __attribute__((ext_vector_type(4))) float f32x4;

// RNE fp32 -> bf16 bit conversion (inputs finite)
__device__ inline unsigned short f2bf(float f) {
  unsigned int u = __float_as_uint(f);
  unsigned int r = u + 0x7FFFu + ((u >> 16) & 1u);
  return (unsigned short)(r >> 16);
}
__device__ inline float bf2f(unsigned short s) {
  return __uint_as_float(((unsigned int)s) << 16);
}
__device__ inline void split2(float f, unsigned short& h, unsigned short& l) {
  h = f2bf(f);
  l = f2bf(f - bf2f(h));
}

#define GLOAD16(g, l) __builtin_amdgcn_global_load_lds( \
    (const __attribute__((address_space(1))) void*)(g), \
    (__attribute__((address_space(3))) void*)(l), 16, 0, 0)

// ---------------- preprocessing (once per call; layer-invariant) ----------------

__global__ void deg_count_kernel(const int* __restrict__ dst,
                                 const float* __restrict__ w,
                                 float* __restrict__ deg,
                                 int* __restrict__ cnt, int E) {
  int e = blockIdx.x * blockDim.x + threadIdx.x;
  if (e < E) {
    int d = dst[e];
    atomicAdd(&deg[d], w[e]);
    atomicAdd(&cnt[d], 1);
  }
}

__global__ void dinv_kernel(const float* __restrict__ deg,
                            float* __restrict__ dinv, int n) {
  int i = blockIdx.x * blockDim.x + threadIdx.x;
  if (i < n) {
    float d = deg[i];
    dinv[i] = (d > 0.f) ? (1.f / sqrtf(d)) : 0.f;
  }
}

__global__ __launch_bounds__(1024)
void scan_kernel(const int* __restrict__ cnt, int* __restrict__ offs,
                 int* __restrict__ cursor, int n) {
  __shared__ int wsums[16];
  __shared__ int carry_s;
  int t = threadIdx.x;
  int lane = t & 63, wid = t >> 6;
  if (t == 0) carry_s = 0;
  __syncthreads();
  for (int base = 0; base < n; base += 1024) {
    int i = base + t;
    int v = (i < n) ? cnt[i] : 0;
    int incl = v;
    #pragma unroll
    for (int d = 1; d < 64; d <<= 1) {
      int tmp = __shfl_up(incl, d, 64);
      if (lane >= d) incl += tmp;
    }
    if (lane == 63) wsums[wid] = incl;
    __syncthreads();
    if (t == 0) {
      int s = carry_s;
      #pragma unroll
      for (int k = 0; k < 16; ++k) { int tt = wsums[k]; wsums[k] = s; s += tt; }
      carry_s = s;
    }
    __syncthreads();
    int excl = incl - v + wsums[wid];
    if (i < n) { offs[i] = excl; cursor[i] = excl; }
    __syncthreads();
  }
  if (t == 0) offs[n] = carry_s;
}

__global__ void scatter_kernel(const int* __restrict__ src,
                               const int* __restrict__ dst,
                               const float* __restrict__ w,
                               const float* __restrict__ dinv,
                               int* __restrict__ cursor,
                               int* __restrict__ src_s,
                               float* __restrict__ norm_s, int E) {
  int e = blockIdx.x * blockDim.x + threadIdx.x;
  if (e < E) {
    int s = src[e], d = dst[e];
    int pos = atomicAdd(&cursor[d], 1);
    src_s[pos] = s;
    norm_s[pos] = dinv[s] * w[e] * dinv[d];
  }
}

// split x0 -> hi/lo bf16
__global__ void split_kernel(const float* __restrict__ x,
                             unsigned short* __restrict__ xhi,
                             unsigned short* __restrict__ xlo, int n4) {
  int i = blockIdx.x * blockDim.x + threadIdx.x;
  if (i < n4) {
    float4 v = reinterpret_cast<const float4*>(x)[i];
    ushort4 h, l;
    split2(v.x, h.x, l.x);
    split2(v.y, h.y, l.y);
    split2(v.z, h.z, l.z);
    split2(v.w, h.w, l.w);
    reinterpret_cast<ushort4*>(xhi)[i] = h;
    reinterpret_cast<ushort4*>(xlo)[i] = l;
  }
}

// transpose + split weights: Wt[mat][n][k] = W[mat][k][n], mat = layer*2 + {Wi,Wr}
__global__ __launch_bounds__(256)
void wsplit_kernel(const float* __restrict__ Wi_a,
                   const float* __restrict__ Wr_a,
                   unsigned short* __restrict__ wthi,
                   unsigned short* __restrict__ wtlo) {
  __shared__ float tile[32][33];
  int m6 = blockIdx.x >> 6;            // 0..5
  int tid = blockIdx.x & 63;
  int tk = (tid >> 3) * 32;
  int tn = (tid & 7) * 32;
  int layer = m6 >> 1;
  const float* W = ((m6 & 1) ? Wr_a : Wi_a) + (size_t)layer * FDIM * FDIM;
  int t = threadIdx.x;
  int lr = t >> 3;            // 0..31
  int lc = (t & 7) * 4;       // 0..28
  float4 v = *reinterpret_cast<const float4*>(W + (size_t)(tk + lr) * FDIM + tn + lc);
  tile[lr][lc + 0] = v.x; tile[lr][lc + 1] = v.y;
  tile[lr][lc + 2] = v.z; tile[lr][lc + 3] = v.w;
  __syncthreads();
  ushort4 h, l;
  split2(tile[lc + 0][lr], h.x, l.x);
  split2(tile[lc + 1][lr], h.y, l.y);
  split2(tile[lc + 2][lr], h.z, l.z);
  split2(tile[lc + 3][lr], h.w, l.w);
  size_t o = ((size_t)m6 * FDIM + tn + lr) * FDIM + tk + lc;
  *reinterpret_cast<ushort4*>(wthi + o) = h;
  *reinterpret_cast<ushort4*>(wtlo + o) = l;
}

// ---------------- aggregation on x: aggx = A_norm @ x (gather bf16-hi rows) ----
// one wave per dst node; fp32 accum; writes aggx as split hi/lo bf16.

__global__ __launch_bounds__(256)
void agg_kernel(const unsigned short* __restrict__ xh,
                const float* __restrict__ norm_s,
                const int* __restrict__ src_s,
                const int* __restrict__ offs,
                unsigned short* __restrict__ agh,
                unsigned short* __restrict__ agl, int n) {
  int node = blockIdx.x * 4 + (threadIdx.x >> 6);
  if (node >= n) return;
  int lane = threadIdx.x & 63;
  int beg = offs[node];
  int end = offs[node + 1];
  float a0 = 0.f, a1 = 0.f, a2 = 0.f, a3 = 0.f;
  int j = beg;
  for (; j + 4 <= end; j += 4) {
    int s0 = src_s[j], s1 = src_s[j + 1], s2 = src_s[j + 2], s3 = src_s[j + 3];
    float w0 = norm_s[j], w1 = norm_s[j + 1], w2 = norm_s[j + 2], w3 = norm_s[j + 3];
    ushort4 v0 = *reinterpret_cast<const ushort4*>(xh + (size_t)s0 * FDIM + lane * 4);
    ushort4 v1 = *reinterpret_cast<const ushort4*>(xh + (size_t)s1 * FDIM + lane * 4);
    ushort4 v2 = *reinterpret_cast<const ushort4*>(xh + (size_t)s2 * FDIM + lane * 4);
    ushort4 v3 = *reinterpret_cast<const ushort4*>(xh + (size_t)s3 * FDIM + lane * 4);
    a0 += w0 * bf2f(v0.x) + w1 * bf2f(v1.x) + w2 * bf2f(v2.x) + w3 * bf2f(v3.x);
    a1 += w0 * bf2f(v0.y) + w1 * bf2f(v1.y) + w2 * bf2f(v2.y) + w3 * bf2f(v3.y);
    a2 += w0 * bf2f(v0.z) + w1 * bf2f(v1.z) + w2 * bf2f(v2.z) + w3 * bf2f(v3.z);
    a3 += w0 * bf2f(v0.w) + w1 * bf2f(v1.w) + w2 * bf2f(v2.w) + w3 * bf2f(v3.w);
  }
  for (; j < end; ++j) {
    int s = src_s[j];
    float wv = norm_s[j];
    ushort4 v = *reinterpret_cast<const ushort4*>(xh + (size_t)s * FDIM + lane * 4);
    a0 += wv * bf2f(v.x); a1 += wv * bf2f(v.y);
    a2 += wv * bf2f(v.z); a3 += wv * bf2f(v.w);
  }
  ushort4 hh, ll;
  split2(a0, hh.x, ll.x);
  split2(a1, hh.y, ll.y);
  split2(a2, hh.z, ll.z);
  split2(a3, hh.w, ll.w);
  size_t base = (size_t)node * FDIM + lane * 4;
  *reinterpret_cast<ushort4*>(agh + base) = hh;
  *reinterpret_cast<ushort4*>(agl + base) = ll;
}

// ------- fused dual-A GEMM: xnext = relu(aggx@Wi + x@Wr + b), split output ----
// 128x128 tile, BK=32, 4 waves (2x2), 4x4 16x16x32 frags, 3-term split per side.
// 8 LDS tiles [128 rows][32 k] bf16, XOR swizzle slot^=(row>>1)&3 (both sides).

#define STAGE_TILE(TI, GPTR, ROWB, CLAMP)                                        \
  {                                                                              \
    int s0 = t;                                                                  \
    int rr = s0 >> 2;                                                            \
    int sl = (s0 & 3) ^ ((rr >> 1) & 3);                                         \
    int r2 = (ROWB) + rr; if (CLAMP && r2 >= M) r2 = M - 1;                      \
    GLOAD16((GPTR) + (size_t)r2 * FDIM + k0 + sl * 8, smem + (TI)*8192 + s0*16); \
    int s1 = t + 256;                                                            \
    rr = s1 >> 2;                                                                \
    sl = (s1 & 3) ^ ((rr >> 1) & 3);                                             \
    r2 = (ROWB) + rr; if (CLAMP && r2 >= M) r2 = M - 1;                          \
    GLOAD16((GPTR) + (size_t)r2 * FDIM + k0 + sl * 8, smem + (TI)*8192 + s1*16); \
  }

__global__ __launch_bounds__(256, 2)
void gemm_dual_kernel(const unsigned short* __restrict__ agh,
                      const unsigned short* __restrict__ agl,
                      const unsigned short* __restrict__ xh,
                      const unsigned short* __restrict__ xl,
                      const unsigned short* __restrict__ wih,
                      const unsigned short* __restrict__ wil,
                      const unsigned short* __restrict__ wrh,
                      const unsigned short* __restrict__ wrl,
                      const float* __restrict__ bias,
                      unsigned short* __restrict__ oh,
                      unsigned short* __restrict__ ol,
                      float* __restrict__ ofinal,
                      int writeFinal, int M) {
  __shared__ __align__(16) unsigned char smem[65536];
  const int t = threadIdx.x;
  const int lane = t & 63;
  const int w = t >> 6;
  const int rowBase = blockIdx.x * 128;
  const int nBase = blockIdx.y * 128;

  const int wm = (w >> 1) * 64;
  const int wn = (w & 1) * 64;

  f32x4 acc[4][4];
  #pragma unroll
  for (int i = 0; i < 4; ++i)
    #pragma unroll
    for (int j = 0; j < 4; ++j)
      acc[i][j] = (f32x4)(0.f);

  for (int k0 = 0; k0 < FDIM; k0 += 32) {
    STAGE_TILE(0, agh, rowBase, 1);
    STAGE_TILE(1, agl, rowBase, 1);
    STAGE_TILE(2, xh, rowBase, 1);
    STAGE_TILE(3, xl, rowBase, 1);
    STAGE_TILE(4, wih, nBase, 0);
    STAGE_TILE(5, wil, nBase, 0);
    STAGE_TILE(6, wrh, nBase, 0);
    STAGE_TILE(7, wrl, nBase, 0);
    __syncthreads();

    const int q = lane >> 4;
    bf16x8 fah[4], fal[4], fxh[4], fxl[4];
    #pragma unroll
    for (int i = 0; i < 4; ++i) {
      int R = wm + i * 16 + (lane & 15);
      int offA = R * 64 + ((q ^ ((R >> 1) & 3)) * 16);
      fah[i] = *reinterpret_cast<const bf16x8*>(smem + offA);
      fal[i] = *reinterpret_cast<const bf16x8*>(smem + 8192 + offA);
      fxh[i] = *reinterpret_cast<const bf16x8*>(smem + 16384 + offA);
      fxl[i] = *reinterpret_cast<const bf16x8*>(smem + 24576 + offA);
    }
    #pragma unroll
    for (int j = 0; j < 4; ++j) {
      int Rb = wn + j * 16 + (lane & 15);
      int offB = Rb * 64 + ((q ^ ((Rb >> 1) & 3)) * 16);
      bf16x8 bwih = *reinterpret_cast<const bf16x8*>(smem + 32768 + offB);
      bf16x8 bwil = *reinterpret_cast<const bf16x8*>(smem + 40960 + offB);
      bf16x8 bwrh = *reinterpret_cast<const bf16x8*>(smem + 49152 + offB);
      bf16x8 bwrl = *reinterpret_cast<const bf16x8*>(smem + 57344 + offB);
      #pragma unroll
      for (int i = 0; i < 4; ++i) {
        acc[i][j] = __builtin_amdgcn_mfma_f32_16x16x32_bf16(fal[i], bwih, acc[i][j], 0, 0, 0);
        acc[i][j] = __builtin_amdgcn_mfma_f32_16x16x32_bf16(fah[i], bwil, acc[i][j], 0, 0, 0);
        acc[i][j] = __builtin_amdgcn_mfma_f32_16x16x32_bf16(fah[i], bwih, acc[i][j], 0, 0, 0);
        acc[i][j] = __builtin_amdgcn_mfma_f32_16x16x32_bf16(fxl[i], bwrh, acc[i][j], 0, 0, 0);
        acc[i][j] = __builtin_amdgcn_mfma_f32_16x16x32_bf16(fxh[i], bwrl, acc[i][j], 0, 0, 0);
        acc[i][j] = __builtin_amdgcn_mfma_f32_16x16x32_bf16(fxh[i], bwrh, acc[i][j], 0, 0, 0);
      }
    }
    __syncthreads();
  }

  const int cr = lane & 15;
  const int r4 = (lane >> 4) * 4;
  #pragma unroll
  for (int i = 0; i < 4; ++i)
    #pragma unroll
    for (int j = 0; j < 4; ++j) {
      int col = nBase + wn + j * 16 + cr;
      float badd = bias[col];
      #pragma unroll
      for (int e = 0; e < 4; ++e) {
        int row = rowBase + wm + i * 16 + r4 + e;
        if (row < M) {
          float val = fmaxf(acc[i][j][e] + badd, 0.f);
          size_t o = (size_t)row * FDIM + col;
          if (writeFinal) {
            ofinal[o] = val;
          } else {
            unsigned short hh, ll;
            split2(val, hh, ll);
            oh[o] = hh;
            ol[o] = ll;
          }
        }
      }
    }
}

// ---------------- launch ----------------

extern "C" void kernel_launch(void* const* d_in, const int* in_sizes, int n_in,
                              void* d_out, int out_size, void* d_ws, size_t ws_size,
                              hipStream_t stream) {
  (void)in_sizes; (void)n_in; (void)out_size; (void)ws_size;
  const float* x0   = (const float*)d_in[0];
  const int*   ei   = (const int*)d_in[1];
  const float* ea   = (const float*)d_in[2];
  const float* Wi_a = (const float*)d_in[3];
  const float* Wr_a = (const float*)d_in[4];
  const float* b_a  = (const float*)d_in[5];
  float* out = (float*)d_out;

  const int* src = ei;
  const int* dst = ei + N_EDGES;

  char* ws = (char*)d_ws;
  size_t off = 0;
  auto alloc = [&](size_t bytes) {
    char* p = ws + off;
    off += (bytes + 255) & ~(size_t)255;
    return p;
  };
  const size_t NF2 = (size_t)N_NODES * FDIM * 2;
  unsigned short* XAh = (unsigned short*)alloc(NF2);
  unsigned short* XAl = (unsigned short*)alloc(NF2);
  unsigned short* XBh = (unsigned short*)alloc(NF2);
  unsigned short* XBl = (unsigned short*)alloc(NF2);
  unsigned short* agh = (unsigned short*)alloc(NF2);
  unsigned short* agl = (unsigned short*)alloc(NF2);
  unsigned short* wthi = (unsigned short*)alloc((size_t)N_LAYERS * 2 * FDIM * FDIM * 2);
  unsigned short* wtlo = (unsigned short*)alloc((size_t)N_LAYERS * 2 * FDIM * FDIM * 2);
  float* deg    = (float*)alloc((size_t)N_NODES * 4);
  float* dinv   = (float*)alloc((size_t)N_NODES * 4);
  int*   cnt    = (int*)alloc((size_t)N_NODES * 4);
  int*   offs   = (int*)alloc((size_t)(N_NODES + 1) * 4);
  int*   cursor = (int*)alloc((size_t)N_NODES * 4);
  int*   src_s  = (int*)alloc((size_t)N_EDGES * 4);
  float* norm_s = (float*)alloc((size_t)N_EDGES * 4);

  hipMemsetAsync(deg, 0, (size_t)N_NODES * 4, stream);
  hipMemsetAsync(cnt, 0, (size_t)N_NODES * 4, stream);

  deg_count_kernel<<<(N_EDGES + 255) / 256, 256, 0, stream>>>(dst, ea, deg, cnt, N_EDGES);
  dinv_kernel<<<(N_NODES + 255) / 256, 256, 0, stream>>>(deg, dinv, N_NODES);
  scan_kernel<<<1, 1024, 0, stream>>>(cnt, offs, cursor, N_NODES);
  scatter_kernel<<<(N_EDGES + 255) / 256, 256, 0, stream>>>(src, dst, ea, dinv, cursor,
                                                            src_s, norm_s, N_EDGES);
  wsplit_kernel<<<6 * 64, 256, 0, stream>>>(Wi_a, Wr_a, wthi, wtlo);
  int n4 = N_NODES * FDIM / 4;
  split_kernel<<<(n4 + 255) / 256, 256, 0, stream>>>(x0, XAh, XAl, n4);

  const size_t WMAT = (size_t)FDIM * FDIM;
  dim3 ggrid((N_NODES + 127) / 128, 2);
  unsigned short* curh = XAh; unsigned short* curl = XAl;
  unsigned short* nxth = XBh; unsigned short* nxtl = XBl;
  for (int l = 0; l < N_LAYERS; ++l) {
    agg_kernel<<<(N_NODES + 3) / 4, 256, 0, stream>>>(curh, norm_s, src_s, offs,
                                                      agh, agl, N_NODES);
    int writeFinal = (l == N_LAYERS - 1) ? 1 : 0;
    gemm_dual_kernel<<<ggrid, 256, 0, stream>>>(
        agh, agl, curh, curl,
        wthi + (size_t)(l * 2) * WMAT, wtlo + (size_t)(l * 2) * WMAT,
        wthi + (size_t)(l * 2 + 1) * WMAT, wtlo + (size_t)(l * 2 + 1) * WMAT,
        b_a + (size_t)l * FDIM,
        nxth, nxtl, out, writeFinal, N_NODES);
    unsigned short* th = curh; unsigned short* tl = curl;
    curh = nxth; curl = nxtl; nxth = th; nxtl = tl;
  }
}

// Round 7
// 666.471 us; speedup vs baseline: 1.7321x; 1.1002x over previous
//
#include <hip/hip_runtime.h>
#include <hip/hip_bf16.h>

#define N_NODES 50000
#define N_EDGES 800000
#define FDIM 256
#define N_LAYERS 3
#define NB_SCAN ((N_NODES + 255) / 256)

typedef __attribute__((ext_vector_type(8))) short bf16x8;
typedef __attribute__((ext_vector_type(4))) float f32x4;

// RNE fp32 -> bf16 bit conversion (inputs finite)
__device__ inline unsigned short f2bf(float f) {
  unsigned int u = __float_as_uint(f);
  unsigned int r = u + 0x7FFFu + ((u >> 16) & 1u);
  return (unsigned short)(r >> 16);
}
__device__ inline float bf2f(unsigned short s) {
  return __uint_as_float(((unsigned int)s) << 16);
}
__device__ inline void split2(float f, unsigned short& h, unsigned short& l) {
  h = f2bf(f);
  l = f2bf(f - bf2f(h));
}

#define GLOAD16(g, l) __builtin_amdgcn_global_load_lds( \
    (const __attribute__((address_space(1))) void*)(g), \
    (__attribute__((address_space(3))) void*)(l), 16, 0, 0)

// ---------------- preprocessing (once per call; layer-invariant) ----------------

__global__ void deg_count_kernel(const int* __restrict__ dst,
                                 const float* __restrict__ w,
                                 float* __restrict__ deg,
                                 int* __restrict__ cnt, int E) {
  int e = blockIdx.x * blockDim.x + threadIdx.x;
  if (e < E) {
    int d = dst[e];
    atomicAdd(&deg[d], w[e]);
    atomicAdd(&cnt[d], 1);
  }
}

__global__ void dinv_kernel(const float* __restrict__ deg,
                            float* __restrict__ dinv, int n) {
  int i = blockIdx.x * blockDim.x + threadIdx.x;
  if (i < n) {
    float d = deg[i];
    dinv[i] = (d > 0.f) ? (1.f / sqrtf(d)) : 0.f;
  }
}

// multi-block scan: per-block sums -> 1-block scan of sums -> per-block offsets
__global__ __launch_bounds__(256)
void blocksum_kernel(const int* __restrict__ cnt, int* __restrict__ bsum, int n) {
  int b = blockIdx.x;
  int t = threadIdx.x;
  int i = b * 256 + t;
  int v = (i < n) ? cnt[i] : 0;
  #pragma unroll
  for (int d = 1; d < 64; d <<= 1) v += __shfl_xor(v, d, 64);
  __shared__ int ws[4];
  if ((t & 63) == 0) ws[t >> 6] = v;
  __syncthreads();
  if (t == 0) bsum[b] = ws[0] + ws[1] + ws[2] + ws[3];
}

__global__ __launch_bounds__(256)
void scanb_kernel(const int* __restrict__ bsum, int* __restrict__ bpre,
                  int* __restrict__ offs_end) {
  int t = threadIdx.x;
  int lane = t & 63, wid = t >> 6;
  int v = (t < NB_SCAN) ? bsum[t] : 0;
  int incl = v;
  #pragma unroll
  for (int d = 1; d < 64; d <<= 1) {
    int tmp = __shfl_up(incl, d, 64);
    if (lane >= d) incl += tmp;
  }
  __shared__ int wsum[4];
  if (lane == 63) wsum[wid] = incl;
  __syncthreads();
  if (t == 0) {
    int s = 0;
    #pragma unroll
    for (int k = 0; k < 4; ++k) { int tt = wsum[k]; wsum[k] = s; s += tt; }
  }
  __syncthreads();
  int excl = incl - v + wsum[wid];
  if (t < NB_SCAN) bpre[t] = excl;
  if (t == NB_SCAN - 1) *offs_end = excl + v;
}

__global__ __launch_bounds__(256)
void offs_kernel(const int* __restrict__ cnt, const int* __restrict__ bpre,
                 int* __restrict__ offs, int* __restrict__ cursor, int n) {
  int b = blockIdx.x;
  int t = threadIdx.x;
  int lane = t & 63, wid = t >> 6;
  int i = b * 256 + t;
  int v = (i < n) ? cnt[i] : 0;
  int incl = v;
  #pragma unroll
  for (int d = 1; d < 64; d <<= 1) {
    int tmp = __shfl_up(incl, d, 64);
    if (lane >= d) incl += tmp;
  }
  __shared__ int wsum[4];
  if (lane == 63) wsum[wid] = incl;
  __syncthreads();
  if (t == 0) {
    int s = 0;
    #pragma unroll
    for (int k = 0; k < 4; ++k) { int tt = wsum[k]; wsum[k] = s; s += tt; }
  }
  __syncthreads();
  int excl = incl - v + wsum[wid] + bpre[b];
  if (i < n) { offs[i] = excl; cursor[i] = excl; }
}

__global__ void scatter_kernel(const int* __restrict__ src,
                               const int* __restrict__ dst,
                               const float* __restrict__ w,
                               const float* __restrict__ dinv,
                               int* __restrict__ cursor,
                               int* __restrict__ src_s,
                               float* __restrict__ norm_s, int E) {
  int e = blockIdx.x * blockDim.x + threadIdx.x;
  if (e < E) {
    int s = src[e], d = dst[e];
    int pos = atomicAdd(&cursor[d], 1);
    src_s[pos] = s;
    norm_s[pos] = dinv[s] * w[e] * dinv[d];
  }
}

// split x0 -> hi/lo bf16
__global__ void split_kernel(const float* __restrict__ x,
                             unsigned short* __restrict__ xhi,
                             unsigned short* __restrict__ xlo, int n4) {
  int i = blockIdx.x * blockDim.x + threadIdx.x;
  if (i < n4) {
    float4 v = reinterpret_cast<const float4*>(x)[i];
    ushort4 h, l;
    split2(v.x, h.x, l.x);
    split2(v.y, h.y, l.y);
    split2(v.z, h.z, l.z);
    split2(v.w, h.w, l.w);
    reinterpret_cast<ushort4*>(xhi)[i] = h;
    reinterpret_cast<ushort4*>(xlo)[i] = l;
  }
}

// transpose + split weights: Wt[mat][n][k] = W[mat][k][n], mat = layer*2 + {Wi,Wr}
__global__ __launch_bounds__(256)
void wsplit_kernel(const float* __restrict__ Wi_a,
                   const float* __restrict__ Wr_a,
                   unsigned short* __restrict__ wthi,
                   unsigned short* __restrict__ wtlo) {
  __shared__ float tile[32][33];
  int m6 = blockIdx.x >> 6;            // 0..5
  int tid = blockIdx.x & 63;
  int tk = (tid >> 3) * 32;
  int tn = (tid & 7) * 32;
  int layer = m6 >> 1;
  const float* W = ((m6 & 1) ? Wr_a : Wi_a) + (size_t)layer * FDIM * FDIM;
  int t = threadIdx.x;
  int lr = t >> 3;            // 0..31
  int lc = (t & 7) * 4;       // 0..28
  float4 v = *reinterpret_cast<const float4*>(W + (size_t)(tk + lr) * FDIM + tn + lc);
  tile[lr][lc + 0] = v.x; tile[lr][lc + 1] = v.y;
  tile[lr][lc + 2] = v.z; tile[lr][lc + 3] = v.w;
  __syncthreads();
  ushort4 h, l;
  split2(tile[lc + 0][lr], h.x, l.x);
  split2(tile[lc + 1][lr], h.y, l.y);
  split2(tile[lc + 2][lr], h.z, l.z);
  split2(tile[lc + 3][lr], h.w, l.w);
  size_t o = ((size_t)m6 * FDIM + tn + lr) * FDIM + tk + lc;
  *reinterpret_cast<ushort4*>(wthi + o) = h;
  *reinterpret_cast<ushort4*>(wtlo + o) = l;
}

// ---------------- aggregation on x: aggx = A_norm @ x (gather bf16-hi rows) ----

__global__ __launch_bounds__(256)
void agg_kernel(const unsigned short* __restrict__ xh,
                const float* __restrict__ norm_s,
                const int* __restrict__ src_s,
                const int* __restrict__ offs,
                unsigned short* __restrict__ agh,
                unsigned short* __restrict__ agl, int n) {
  int node = blockIdx.x * 4 + (threadIdx.x >> 6);
  if (node >= n) return;
  int lane = threadIdx.x & 63;
  int beg = offs[node];
  int end = offs[node + 1];
  float a0 = 0.f, a1 = 0.f, a2 = 0.f, a3 = 0.f;
  int j = beg;
  for (; j + 4 <= end; j += 4) {
    int s0 = src_s[j], s1 = src_s[j + 1], s2 = src_s[j + 2], s3 = src_s[j + 3];
    float w0 = norm_s[j], w1 = norm_s[j + 1], w2 = norm_s[j + 2], w3 = norm_s[j + 3];
    ushort4 v0 = *reinterpret_cast<const ushort4*>(xh + (size_t)s0 * FDIM + lane * 4);
    ushort4 v1 = *reinterpret_cast<const ushort4*>(xh + (size_t)s1 * FDIM + lane * 4);
    ushort4 v2 = *reinterpret_cast<const ushort4*>(xh + (size_t)s2 * FDIM + lane * 4);
    ushort4 v3 = *reinterpret_cast<const ushort4*>(xh + (size_t)s3 * FDIM + lane * 4);
    a0 += w0 * bf2f(v0.x) + w1 * bf2f(v1.x) + w2 * bf2f(v2.x) + w3 * bf2f(v3.x);
    a1 += w0 * bf2f(v0.y) + w1 * bf2f(v1.y) + w2 * bf2f(v2.y) + w3 * bf2f(v3.y);
    a2 += w0 * bf2f(v0.z) + w1 * bf2f(v1.z) + w2 * bf2f(v2.z) + w3 * bf2f(v3.z);
    a3 += w0 * bf2f(v0.w) + w1 * bf2f(v1.w) + w2 * bf2f(v2.w) + w3 * bf2f(v3.w);
  }
  for (; j < end; ++j) {
    int s = src_s[j];
    float wv = norm_s[j];
    ushort4 v = *reinterpret_cast<const ushort4*>(xh + (size_t)s * FDIM + lane * 4);
    a0 += wv * bf2f(v.x); a1 += wv * bf2f(v.y);
    a2 += wv * bf2f(v.z); a3 += wv * bf2f(v.w);
  }
  ushort4 hh, ll;
  split2(a0, hh.x, ll.x);
  split2(a1, hh.y, ll.y);
  split2(a2, hh.z, ll.z);
  split2(a3, hh.w, ll.w);
  size_t base = (size_t)node * FDIM + lane * 4;
  *reinterpret_cast<ushort4*>(agh + base) = hh;
  *reinterpret_cast<ushort4*>(agl + base) = ll;
}

// ------- fused dual-A GEMM: xnext = relu(aggx@Wi + x@Wr + b), split output ----
// 128x128 tile, BK=32, 4 waves (2x2), 4x4 16x16x32 frags, 3-term split per side.
// Single 64KB LDS buffer; per K-step: ds_read ALL frags -> lgkmcnt(0)+raw
// s_barrier -> issue next-step global_load_lds (overlaps MFMA) -> 96 MFMA.
// Top-of-step __syncthreads() is the single vmcnt drain (2-phase minimum recipe).
// Block pairing: bid = row*2 + nb so the A-panel re-read has reuse distance 1.

#define STAGE_TILE(TI, GPTR, ROWB, CLAMP, K0)                                     \
  {                                                                               \
    int s0_ = t;                                                                  \
    int rr_ = s0_ >> 2;                                                           \
    int sl_ = (s0_ & 3) ^ ((rr_ >> 1) & 3);                                       \
    int r2_ = (ROWB) + rr_; if (CLAMP && r2_ >= M) r2_ = M - 1;                   \
    GLOAD16((GPTR) + (size_t)r2_ * FDIM + (K0) + sl_ * 8,                         \
            smem + (TI) * 8192 + s0_ * 16);                                       \
    int s1_ = t + 256;                                                            \
    rr_ = s1_ >> 2;                                                               \
    sl_ = (s1_ & 3) ^ ((rr_ >> 1) & 3);                                           \
    r2_ = (ROWB) + rr_; if (CLAMP && r2_ >= M) r2_ = M - 1;                       \
    GLOAD16((GPTR) + (size_t)r2_ * FDIM + (K0) + sl_ * 8,                         \
            smem + (TI) * 8192 + s1_ * 16);                                       \
  }

#define STAGE_ALL(K0)                      \
  STAGE_TILE(0, agh, rowBase, 1, K0);      \
  STAGE_TILE(1, agl, rowBase, 1, K0);      \
  STAGE_TILE(2, xh, rowBase, 1, K0);       \
  STAGE_TILE(3, xl, rowBase, 1, K0);       \
  STAGE_TILE(4, wih, nBase, 0, K0);        \
  STAGE_TILE(5, wil, nBase, 0, K0);        \
  STAGE_TILE(6, wrh, nBase, 0, K0);        \
  STAGE_TILE(7, wrl, nBase, 0, K0);

__global__ __launch_bounds__(256, 2)
void gemm_dual_kernel(const unsigned short* __restrict__ agh,
                      const unsigned short* __restrict__ agl,
                      const unsigned short* __restrict__ xh,
                      const unsigned short* __restrict__ xl,
                      const unsigned short* __restrict__ wih,
                      const unsigned short* __restrict__ wil,
                      const unsigned short* __restrict__ wrh,
                      const unsigned short* __restrict__ wrl,
                      const float* __restrict__ bias,
                      unsigned short* __restrict__ oh,
                      unsigned short* __restrict__ ol,
                      float* __restrict__ ofinal,
                      int writeFinal, int M) {
  __shared__ __align__(16) unsigned char smem[65536];
  const int t = threadIdx.x;
  const int lane = t & 63;
  const int w = t >> 6;
  const int bid = blockIdx.x;
  const int rowBase = (bid >> 1) * 128;
  const int nBase = (bid & 1) * 128;

  const int wm = (w >> 1) * 64;
  const int wn = (w & 1) * 64;

  f32x4 acc[4][4];
  #pragma unroll
  for (int i = 0; i < 4; ++i)
    #pragma unroll
    for (int j = 0; j < 4; ++j)
      acc[i][j] = (f32x4)(0.f);

  // prologue: stage K-step 0
  STAGE_ALL(0);

  for (int s = 0; s < 8; ++s) {
    __syncthreads();   // drains vmcnt(0): staged data landed for this step

    const int q = lane >> 4;
    bf16x8 fah[4], fal[4], fxh[4], fxl[4];
    bf16x8 bih[4], bil[4], brh[4], brl[4];
    #pragma unroll
    for (int i = 0; i < 4; ++i) {
      int R = wm + i * 16 + (lane & 15);
      int offA = R * 64 + ((q ^ ((R >> 1) & 3)) * 16);
      fah[i] = *reinterpret_cast<const bf16x8*>(smem + offA);
      fal[i] = *reinterpret_cast<const bf16x8*>(smem + 8192 + offA);
      fxh[i] = *reinterpret_cast<const bf16x8*>(smem + 16384 + offA);
      fxl[i] = *reinterpret_cast<const bf16x8*>(smem + 24576 + offA);
      int Rb = wn + i * 16 + (lane & 15);
      int offB = Rb * 64 + ((q ^ ((Rb >> 1) & 3)) * 16);
      bih[i] = *reinterpret_cast<const bf16x8*>(smem + 32768 + offB);
      bil[i] = *reinterpret_cast<const bf16x8*>(smem + 40960 + offB);
      brh[i] = *reinterpret_cast<const bf16x8*>(smem + 49152 + offB);
      brl[i] = *reinterpret_cast<const bf16x8*>(smem + 57344 + offB);
    }
    // all LDS reads in registers before the buffer is overwritten
    asm volatile("s_waitcnt lgkmcnt(0)" ::: "memory");
    __builtin_amdgcn_sched_barrier(0);
    __builtin_amdgcn_s_barrier();      // raw barrier: no vmcnt drain
    __builtin_amdgcn_sched_barrier(0);

    if (s < 7) {
      int k1 = (s + 1) * 32;
      STAGE_ALL(k1);                   // flies under the MFMA cluster below
    }

    #pragma unroll
    for (int j = 0; j < 4; ++j) {
      #pragma unroll
      for (int i = 0; i < 4; ++i) {
        acc[i][j] = __builtin_amdgcn_mfma_f32_16x16x32_bf16(fal[i], bih[j], acc[i][j], 0, 0, 0);
        acc[i][j] = __builtin_amdgcn_mfma_f32_16x16x32_bf16(fah[i], bil[j], acc[i][j], 0, 0, 0);
        acc[i][j] = __builtin_amdgcn_mfma_f32_16x16x32_bf16(fah[i], bih[j], acc[i][j], 0, 0, 0);
        acc[i][j] = __builtin_amdgcn_mfma_f32_16x16x32_bf16(fxl[i], brh[j], acc[i][j], 0, 0, 0);
        acc[i][j] = __builtin_amdgcn_mfma_f32_16x16x32_bf16(fxh[i], brl[j], acc[i][j], 0, 0, 0);
        acc[i][j] = __builtin_amdgcn_mfma_f32_16x16x32_bf16(fxh[i], brh[j], acc[i][j], 0, 0, 0);
      }
    }
  }

  const int cr = lane & 15;
  const int r4 = (lane >> 4) * 4;
  #pragma unroll
  for (int i = 0; i < 4; ++i)
    #pragma unroll
    for (int j = 0; j < 4; ++j) {
      int col = nBase + wn + j * 16 + cr;
      float badd = bias[col];
      #pragma unroll
      for (int e = 0; e < 4; ++e) {
        int row = rowBase + wm + i * 16 + r4 + e;
        if (row < M) {
          float val = fmaxf(acc[i][j][e] + badd, 0.f);
          size_t o = (size_t)row * FDIM + col;
          if (writeFinal) {
            ofinal[o] = val;
          } else {
            unsigned short hh, ll;
            split2(val, hh, ll);
            oh[o] = hh;
            ol[o] = ll;
          }
        }
      }
    }
}

// ---------------- launch ----------------

extern "C" void kernel_launch(void* const* d_in, const int* in_sizes, int n_in,
                              void* d_out, int out_size, void* d_ws, size_t ws_size,
                              hipStream_t stream) {
  (void)in_sizes; (void)n_in; (void)out_size; (void)ws_size;
  const float* x0   = (const float*)d_in[0];
  const int*   ei   = (const int*)d_in[1];
  const float* ea   = (const float*)d_in[2];
  const float* Wi_a = (const float*)d_in[3];
  const float* Wr_a = (const float*)d_in[4];
  const float* b_a  = (const float*)d_in[5];
  float* out = (float*)d_out;

  const int* src = ei;
  const int* dst = ei + N_EDGES;

  char* ws = (char*)d_ws;
  size_t off = 0;
  auto alloc = [&](size_t bytes) {
    char* p = ws + off;
    off += (bytes + 255) & ~(size_t)255;
    return p;
  };
  const size_t NF2 = (size_t)N_NODES * FDIM * 2;
  unsigned short* XAh = (unsigned short*)alloc(NF2);
  unsigned short* XAl = (unsigned short*)alloc(NF2);
  unsigned short* XBh = (unsigned short*)alloc(NF2);
  unsigned short* XBl = (unsigned short*)alloc(NF2);
  unsigned short* agh = (unsigned short*)alloc(NF2);
  unsigned short* agl = (unsigned short*)alloc(NF2);
  unsigned short* wthi = (unsigned short*)alloc((size_t)N_LAYERS * 2 * FDIM * FDIM * 2);
  unsigned short* wtlo = (unsigned short*)alloc((size_t)N_LAYERS * 2 * FDIM * FDIM * 2);
  float* deg    = (float*)alloc((size_t)N_NODES * 4);
  float* dinv   = (float*)alloc((size_t)N_NODES * 4);
  int*   cnt    = (int*)alloc((size_t)N_NODES * 4);
  int*   offs   = (int*)alloc((size_t)(N_NODES + 1) * 4);
  int*   cursor = (int*)alloc((size_t)N_NODES * 4);
  int*   src_s  = (int*)alloc((size_t)N_EDGES * 4);
  float* norm_s = (float*)alloc((size_t)N_EDGES * 4);
  int*   bsum   = (int*)alloc((size_t)NB_SCAN * 4);
  int*   bpre   = (int*)alloc((size_t)NB_SCAN * 4);

  hipMemsetAsync(deg, 0, (size_t)N_NODES * 4, stream);
  hipMemsetAsync(cnt, 0, (size_t)N_NODES * 4, stream);

  deg_count_kernel<<<(N_EDGES + 255) / 256, 256, 0, stream>>>(dst, ea, deg, cnt, N_EDGES);
  dinv_kernel<<<(N_NODES + 255) / 256, 256, 0, stream>>>(deg, dinv, N_NODES);
  blocksum_kernel<<<NB_SCAN, 256, 0, stream>>>(cnt, bsum, N_NODES);
  scanb_kernel<<<1, 256, 0, stream>>>(bsum, bpre, offs + N_NODES);
  offs_kernel<<<NB_SCAN, 256, 0, stream>>>(cnt, bpre, offs, cursor, N_NODES);
  scatter_kernel<<<(N_EDGES + 255) / 256, 256, 0, stream>>>(src, dst, ea, dinv, cursor,
                                                            src_s, norm_s, N_EDGES);
  wsplit_kernel<<<6 * 64, 256, 0, stream>>>(Wi_a, Wr_a, wthi, wtlo);
  int n4 = N_NODES * FDIM / 4;
  split_kernel<<<(n4 + 255) / 256, 256, 0, stream>>>(x0, XAh, XAl, n4);

  const size_t WMAT = (size_t)FDIM * FDIM;
  int nrow = (N_NODES + 127) / 128;
  dim3 ggrid(nrow * 2);
  unsigned short* curh = XAh; unsigned short* curl = XAl;
  unsigned short* nxth = XBh; unsigned short* nxtl = XBl;
  for (int l = 0; l < N_LAYERS; ++l) {
    agg_kernel<<<(N_NODES + 3) / 4, 256, 0, stream>>>(curh, norm_s, src_s, offs,
                                                      agh, agl, N_NODES);
    int writeFinal = (l == N_LAYERS - 1) ? 1 : 0;
    gemm_dual_kernel<<<ggrid, 256, 0, stream>>>(
        agh, agl, curh, curl,
        wthi + (size_t)(l * 2) * WMAT, wtlo + (size_t)(l * 2) * WMAT,
        wthi + (size_t)(l * 2 + 1) * WMAT, wtlo + (size_t)(l * 2 + 1) * WMAT,
        b_a + (size_t)l * FDIM,
        nxth, nxtl, out, writeFinal, N_NODES);
    unsigned short* th = curh; unsigned short* tl = curl;
    curh = nxth; curl = nxtl; nxth = th; nxtl = tl;
  }
}